// Round 2
// baseline (283.265 us; speedup 1.0000x reference)
//
#include <hip/hip_runtime.h>

#define CROP 81
#define NB   64
#define IMH  512
#define IMW  512

// total output pixels: N*6*81*81
#define TOTAL (NB * 6 * CROP * CROP)
#define IMG_OUT_ELEMS (NB * 6 * 3 * CROP * CROP)   // 7,558,272

__global__ __launch_bounds__(256) void selectnet_kernel(
    const float* __restrict__ img,     // (64,3,512,512)
    const int*   __restrict__ label,   // (64,512,512)
    const float* __restrict__ points,  // (64,9,2)
    float* __restrict__ out)           // [croped_image | croped_pred]
{
    int idx = blockIdx.x * 256 + threadIdx.x;
    if (idx >= TOTAL) return;

    int j = idx % CROP;
    int t = idx / CROP;
    int i = t % CROP;
    t /= CROP;
    int k = t % 6;
    int n = t / 6;

    // ---- pts6[n,k] = points[n,k+1] for k<5, else mean(points[n,6:9]) ----
    const float* pn = points + n * 18;   // (9,2): [...,0]=py, [...,1]=px
    float py, px;
    if (k < 5) {
        py = pn[(k + 1) * 2 + 0];
        px = pn[(k + 1) * 2 + 1];
    } else {
        // np.mean over 3 elems: ((a+b)+c)/3 in float32
        py = __fdiv_rn(__fadd_rn(__fadd_rn(pn[12], pn[14]), pn[16]), 3.0f);
        px = __fdiv_rn(__fadd_rn(__fadd_rn(pn[13], pn[15]), pn[17]), 3.0f);
    }

    // ---- replicate reference float32 op chain exactly (no FMA contraction) ----
    const float sx = (float)(80.0 / 511.0);   // (CROP-1)/(W-1), dbl->f32 cast
    const float sy = 0.15625f;                // (CROP-1)/H = 80/512, EXACT

    // base = linspace(-1,1,81): j*0.025 (f64) - 1.0 (f64), cast f32
    float basej = (float)((double)j * 0.025 - 1.0);
    float basei = (float)((double)i * 0.025 - 1.0);

    float tx = __fadd_rn(-1.0f, __fdiv_rn(__fmul_rn(2.0f, px), 511.0f));
    float ty = __fadd_rn(-1.0f, __fdiv_rn(__fmul_rn(2.0f, py), 511.0f));

    float gx = __fadd_rn(__fmul_rn(sx, basej), tx);
    float gy = __fadd_rn(__fmul_rn(sy, basei), ty);

    float ix = __fmul_rn(__fmul_rn(__fadd_rn(gx, 1.0f), 0.5f), 511.0f);
    float iy = __fmul_rn(__fmul_rn(__fadd_rn(gy, 1.0f), 0.5f), 511.0f);

    // ================= bilinear sample of img (3 channels) =================
    float x0f = floorf(ix), y0f = floorf(iy);
    float x1f = x0f + 1.0f, y1f = y0f + 1.0f;
    float wx1 = ix - x0f, wx0 = 1.0f - wx1;
    float wy1 = iy - y0f, wy0 = 1.0f - wy1;

    float v00 = (x0f >= 0.0f && x0f <= 511.0f && y0f >= 0.0f && y0f <= 511.0f) ? 1.0f : 0.0f;
    float v10 = (x1f >= 0.0f && x1f <= 511.0f && y0f >= 0.0f && y0f <= 511.0f) ? 1.0f : 0.0f;
    float v01 = (x0f >= 0.0f && x0f <= 511.0f && y1f >= 0.0f && y1f <= 511.0f) ? 1.0f : 0.0f;
    float v11 = (x1f >= 0.0f && x1f <= 511.0f && y1f >= 0.0f && y1f <= 511.0f) ? 1.0f : 0.0f;

    int xi0 = (int)fminf(fmaxf(x0f, 0.0f), 511.0f);
    int xi1 = (int)fminf(fmaxf(x1f, 0.0f), 511.0f);
    int yi0 = (int)fminf(fmaxf(y0f, 0.0f), 511.0f);
    int yi1 = (int)fminf(fmaxf(y1f, 0.0f), 511.0f);

    float w00 = wx0 * wy0, w10 = wx1 * wy0, w01 = wx0 * wy1, w11 = wx1 * wy1;

    const int r0 = yi0 * IMW, r1 = yi1 * IMW;
    const size_t img_n = (size_t)n * 3 * IMH * IMW;
    const size_t out_img_base = ((size_t)(n * 6 + k) * 3) * (CROP * CROP) + i * CROP + j;

    #pragma unroll
    for (int c = 0; c < 3; ++c) {
        const float* ic = img + img_n + (size_t)c * IMH * IMW;
        float g00 = ic[r0 + xi0] * v00;
        float g10 = ic[r0 + xi1] * v10;
        float g01 = ic[r1 + xi0] * v01;
        float g11 = ic[r1 + xi1] * v11;
        float val = ((g00 * w00 + g10 * w10) + g01 * w01) + g11 * w11;
        out[out_img_base + (size_t)c * (CROP * CROP)] = val;
    }

    // ================= nearest sample of label + class transform =================
    float xr = rintf(ix);   // round half-to-even == np.round
    float yr = rintf(iy);
    bool nv = (xr >= 0.0f && xr <= 511.0f && yr >= 0.0f && yr <= 511.0f);
    int xn = (int)fminf(fmaxf(xr, 0.0f), 511.0f);
    int yn = (int)fminf(fmaxf(yr, 0.0f), 511.0f);
    int lab = label[(size_t)n * IMH * IMW + yn * IMW + xn];
    float labv = nv ? (float)lab : 0.0f;

    float pred;
    if (k < 5) {
        pred = (labv == (float)(k + 1)) ? 1.0f : 0.0f;
    } else {
        pred = (labv == 6.0f) ? 1.0f
             : (labv == 7.0f) ? 2.0f
             : (labv == 8.0f) ? 3.0f
             : 0.0f;
    }
    out[IMG_OUT_ELEMS + (size_t)(n * 6 + k) * (CROP * CROP) + i * CROP + j] = pred;
}

extern "C" void kernel_launch(void* const* d_in, const int* in_sizes, int n_in,
                              void* d_out, int out_size, void* d_ws, size_t ws_size,
                              hipStream_t stream) {
    const float* img    = (const float*)d_in[0];
    const int*   label  = (const int*)d_in[1];
    const float* points = (const float*)d_in[2];
    float* out = (float*)d_out;

    int blocks = (TOTAL + 255) / 256;
    selectnet_kernel<<<blocks, 256, 0, stream>>>(img, label, points, out);
}

// Round 4
// 282.785 us; speedup vs baseline: 1.0017x; 1.0017x over previous
//
#include <hip/hip_runtime.h>

#define CROP 81
#define NB   64
#define IMH  512
#define IMW  512

// total output pixels: N*6*81*81
#define TOTAL (NB * 6 * CROP * CROP)
#define IMG_OUT_ELEMS (NB * 6 * 3 * CROP * CROP)   // 7,558,272

__global__ __launch_bounds__(256) void selectnet_kernel(
    const float* __restrict__ img,     // (64,3,512,512)
    const int*   __restrict__ label,   // (64,512,512)
    const float* __restrict__ points,  // (64,9,2)
    float* __restrict__ out)           // [croped_image | croped_pred]
{
    int idx = blockIdx.x * 256 + threadIdx.x;
    if (idx >= TOTAL) return;

    int j = idx % CROP;
    int t = idx / CROP;
    int i = t % CROP;
    t /= CROP;
    int k = t % 6;
    int n = t / 6;

    // ---- pts6[n,k] = points[n,k+1] for k<5, else mean(points[n,6:9]) ----
    const float* pn = points + n * 18;   // (9,2): [...,0]=py, [...,1]=px
    float py, px;
    if (k < 5) {
        py = pn[(k + 1) * 2 + 0];
        px = pn[(k + 1) * 2 + 1];
    } else {
        // np.mean over 3 elems: ((a+b)+c)/3 in float32
        py = __fdiv_rn(__fadd_rn(__fadd_rn(pn[12], pn[14]), pn[16]), 3.0f);
        px = __fdiv_rn(__fadd_rn(__fadd_rn(pn[13], pn[15]), pn[17]), 3.0f);
    }

    // ---- replicate reference float32 op chain exactly (no FMA contraction) ----
    const float sx = (float)(80.0 / 511.0);   // (CROP-1)/(W-1), dbl->f32 cast
    const float sy = 0.15625f;                // (CROP-1)/H = 80/512, EXACT

    // base = linspace(-1,1,81): j*0.025 (f64) - 1.0 (f64), cast f32
    float basej = (float)((double)j * 0.025 - 1.0);
    float basei = (float)((double)i * 0.025 - 1.0);

    float tx = __fadd_rn(-1.0f, __fdiv_rn(__fmul_rn(2.0f, px), 511.0f));
    float ty = __fadd_rn(-1.0f, __fdiv_rn(__fmul_rn(2.0f, py), 511.0f));

    float gx = __fadd_rn(__fmul_rn(sx, basej), tx);
    float gy = __fadd_rn(__fmul_rn(sy, basei), ty);

    float ix = __fmul_rn(__fmul_rn(__fadd_rn(gx, 1.0f), 0.5f), 511.0f);
    float iy = __fmul_rn(__fmul_rn(__fadd_rn(gy, 1.0f), 0.5f), 511.0f);

    // ================= bilinear sample of img (3 channels) =================
    float x0f = floorf(ix), y0f = floorf(iy);
    float x1f = x0f + 1.0f, y1f = y0f + 1.0f;
    float wx1 = ix - x0f, wx0 = 1.0f - wx1;
    float wy1 = iy - y0f, wy0 = 1.0f - wy1;

    float v00 = (x0f >= 0.0f && x0f <= 511.0f && y0f >= 0.0f && y0f <= 511.0f) ? 1.0f : 0.0f;
    float v10 = (x1f >= 0.0f && x1f <= 511.0f && y0f >= 0.0f && y0f <= 511.0f) ? 1.0f : 0.0f;
    float v01 = (x0f >= 0.0f && x0f <= 511.0f && y1f >= 0.0f && y1f <= 511.0f) ? 1.0f : 0.0f;
    float v11 = (x1f >= 0.0f && x1f <= 511.0f && y1f >= 0.0f && y1f <= 511.0f) ? 1.0f : 0.0f;

    int xi0 = (int)fminf(fmaxf(x0f, 0.0f), 511.0f);
    int xi1 = (int)fminf(fmaxf(x1f, 0.0f), 511.0f);
    int yi0 = (int)fminf(fmaxf(y0f, 0.0f), 511.0f);
    int yi1 = (int)fminf(fmaxf(y1f, 0.0f), 511.0f);

    float w00 = wx0 * wy0, w10 = wx1 * wy0, w01 = wx0 * wy1, w11 = wx1 * wy1;

    const int r0 = yi0 * IMW, r1 = yi1 * IMW;
    const size_t img_n = (size_t)n * 3 * IMH * IMW;
    const size_t out_img_base = ((size_t)(n * 6 + k) * 3) * (CROP * CROP) + i * CROP + j;

    #pragma unroll
    for (int c = 0; c < 3; ++c) {
        const float* ic = img + img_n + (size_t)c * IMH * IMW;
        float g00 = ic[r0 + xi0] * v00;
        float g10 = ic[r0 + xi1] * v10;
        float g01 = ic[r1 + xi0] * v01;
        float g11 = ic[r1 + xi1] * v11;
        float val = ((g00 * w00 + g10 * w10) + g01 * w01) + g11 * w11;
        out[out_img_base + (size_t)c * (CROP * CROP)] = val;
    }

    // ================= nearest sample of label + class transform =================
    float xr = rintf(ix);   // round half-to-even == np.round
    float yr = rintf(iy);
    bool nv = (xr >= 0.0f && xr <= 511.0f && yr >= 0.0f && yr <= 511.0f);
    int xn = (int)fminf(fmaxf(xr, 0.0f), 511.0f);
    int yn = (int)fminf(fmaxf(yr, 0.0f), 511.0f);
    int lab = label[(size_t)n * IMH * IMW + yn * IMW + xn];
    float labv = nv ? (float)lab : 0.0f;

    float pred;
    if (k < 5) {
        pred = (labv == (float)(k + 1)) ? 1.0f : 0.0f;
    } else {
        pred = (labv == 6.0f) ? 1.0f
             : (labv == 7.0f) ? 2.0f
             : (labv == 8.0f) ? 3.0f
             : 0.0f;
    }
    out[IMG_OUT_ELEMS + (size_t)(n * 6 + k) * (CROP * CROP) + i * CROP + j] = pred;
}

extern "C" void kernel_launch(void* const* d_in, const int* in_sizes, int n_in,
                              void* d_out, int out_size, void* d_ws, size_t ws_size,
                              hipStream_t stream) {
    const float* img    = (const float*)d_in[0];
    const int*   label  = (const int*)d_in[1];
    const float* points = (const float*)d_in[2];
    float* out = (float*)d_out;

    int blocks = (TOTAL + 255) / 256;
    selectnet_kernel<<<blocks, 256, 0, stream>>>(img, label, points, out);
}